// Round 5
// baseline (179.669 us; speedup 1.0000x reference)
//
#include <hip/hip_runtime.h>

// Problem constants (from reference)
#define N_NODES 16384
#define D_EMB   128
#define LIST_CAP 1024          // max common neighbors (max degree ~200 incl. i==j)
#define BM_WORDS 512           // 16384 bits / 32 per compressed row
#define FLAG_OFF N_NODES       // int index of layout flag, right after used_flags
#define BM_OFF_BYTES (1 << 17) // bitmaps start at 128 KiB into ws
#define WS_NEEDED (BM_OFF_BYTES + (size_t)N_NODES * (BM_WORDS * 4)) // ~33.7 MB

// ---------------------------------------------------------------------------
// Pass 1: zero used-flags; block 0 also probes adjacency encoding.
// int32-bool: first 16384 words all in {0,1}; byte-bool: some word >1 w.p. ~1.
__global__ __launch_bounds__(256) void zero_probe_kernel(
    const unsigned int* __restrict__ words, int* __restrict__ flags)
{
    const int idx = blockIdx.x * 256 + threadIdx.x;  // grid 64 -> 16384 ints
    flags[idx] = 0;
    if (blockIdx.x == 0) {
        __shared__ int s_any;
        if (threadIdx.x == 0) s_any = 0;
        __syncthreads();
        int any = 0;
        for (int k = threadIdx.x; k < 16384; k += 256)
            if (words[k] > 1u) any = 1;
        if (any) atomicOr(&s_any, 1);
        __syncthreads();
        if (threadIdx.x == 0) flags[FLAG_OFF] = s_any;  // 1 => byte layout
    }
}

// Pass 2: mark rows referenced by any link endpoint (idempotent stores).
__global__ __launch_bounds__(256) void mark_kernel(
    const int* __restrict__ links, int* __restrict__ flags, int n_endpoints)
{
    const int k = blockIdx.x * 256 + threadIdx.x;
    if (k < n_endpoints) flags[links[k]] = 1;
}

// Pass 3 (int32 layout): barrier-free ballot compression.
// Wave w, iter k: lane l loads uint4 at u = g*64 + l (lane-contiguous 1KB per
// wave-load), g = w*16 + k. Ballot c: bit l <-> node 256*g + 4*l + c.
// Lane 0 stores the 4 x u64 masks (32B) at dst64 + g*4. PERMUTED layout;
// link kernel inverts it. Self-gates on layout flag.
__global__ __launch_bounds__(256) void compress_ballot_kernel(
    const int* __restrict__ adj, const int* __restrict__ flags,
    unsigned int* __restrict__ bm)
{
    const int r = blockIdx.x;
    if (flags[FLAG_OFF] != 0) return;   // wrong layout for this variant
    if (!flags[r]) return;

    const int lane = threadIdx.x & 63;
    const int wave = threadIdx.x >> 6;

    const uint4* row = reinterpret_cast<const uint4*>(adj + (size_t)r * N_NODES);
    unsigned long long* dst64 =
        reinterpret_cast<unsigned long long*>(bm + (size_t)r * BM_WORDS);

#pragma unroll 4
    for (int k = 0; k < 16; ++k) {
        const int g = wave * 16 + k;
        const uint4 v = row[g * 64 + lane];
        const unsigned long long m0 = __ballot(v.x != 0u);
        const unsigned long long m1 = __ballot(v.y != 0u);
        const unsigned long long m2 = __ballot(v.z != 0u);
        const unsigned long long m3 = __ballot(v.w != 0u);
        if (lane == 0) {
            ulonglong2* p = reinterpret_cast<ulonglong2*>(dst64 + g * 4);
            p[0] = make_ulonglong2(m0, m1);
            p[1] = make_ulonglong2(m2, m3);
        }
    }
}

// Pass 3 (byte layout, defensive): LDS packing, LINEAR bitmap layout.
__global__ __launch_bounds__(256) void compress_byte_kernel(
    const unsigned char* __restrict__ adj, const int* __restrict__ flags,
    unsigned int* __restrict__ bm)
{
    const int r = blockIdx.x;
    if (flags[FLAG_OFF] == 0) return;   // wrong layout for this variant
    if (!flags[r]) return;
    unsigned int* dst = bm + (size_t)r * BM_WORDS;
    const int t = threadIdx.x;
    __shared__ unsigned int s_nib[256];

    const uint4* row = reinterpret_cast<const uint4*>(adj + (size_t)r * N_NODES);
#pragma unroll
    for (int c = 0; c < 4; ++c) {
        const uint4 v = row[c * 256 + t];               // nodes [(c*256+t)*16, +16)
        const unsigned int arr[4] = {v.x, v.y, v.z, v.w};
        unsigned int half = 0;
#pragma unroll
        for (int a = 0; a < 4; ++a)
#pragma unroll
            for (int bb = 0; bb < 4; ++bb)
                half |= ((((arr[a] >> (8 * bb)) & 0xFFu) ? 1u : 0u) << (a * 4 + bb));
        s_nib[t] = half;                                // 16 bits valid
        __syncthreads();
        if (t < 128)
            dst[c * 128 + t] = s_nib[t * 2] | (s_nib[t * 2 + 1] << 16);
        __syncthreads();
    }
}

// Pass 4: per link, AND two 2KB bitmaps, decode set bits -> node indices
// (permuted decode for int32 layout, linear for byte), then write
// [product(128) | cn_sum(128)].
__global__ __launch_bounds__(256) void link_kernel(
    const int* __restrict__ links, const unsigned int* __restrict__ bm,
    const float* __restrict__ emb, float* __restrict__ out,
    const int* __restrict__ flags, int n_links)
{
    const int link = blockIdx.x;
    if (link >= n_links) return;
    const int i = links[2 * link];
    const int j = links[2 * link + 1];
    const int byte_layout = flags[FLAG_OFF];

    __shared__ int s_list[LIST_CAP];
    __shared__ int s_count;
    if (threadIdx.x == 0) s_count = 0;
    __syncthreads();

    const unsigned int* bi = bm + (size_t)i * BM_WORDS;
    const unsigned int* bj = bm + (size_t)j * BM_WORDS;
#pragma unroll
    for (int h = 0; h < 2; ++h) {
        const int w = h * 256 + threadIdx.x;
        unsigned int m = bi[w] & bj[w];
        while (m) {
            const int b = __ffs(m) - 1;
            m &= m - 1;
            const int node = byte_layout
                ? (w * 32 + b)
                : (((w >> 3) << 8) + ((w & 1) << 7) + (b << 2) + ((w >> 1) & 3));
            const int pos = atomicAdd(&s_count, 1);
            if (pos < LIST_CAP) s_list[pos] = node;
        }
    }
    __syncthreads();

    int count = s_count;
    if (count > LIST_CAP) count = LIST_CAP;

    const int t = threadIdx.x;
    const size_t obase = (size_t)link * (2 * D_EMB);
    if (t < D_EMB) {
        out[obase + t] = emb[(size_t)i * D_EMB + t] * emb[(size_t)j * D_EMB + t];
    } else {
        const int d = t - D_EMB;
        float s = 0.0f;
        for (int c = 0; c < count; ++c)
            s += emb[(size_t)s_list[c] * D_EMB + d];
        out[obase + D_EMB + d] = s;
    }
}

// ---------------------------------------------------------------------------
// Fallback (ws too small): direct kernel — reads both full rows per link.
__global__ __launch_bounds__(256) void detect_layout_kernel(
    const unsigned int* __restrict__ words, int* __restrict__ flag)
{
    __shared__ int s_any;
    if (threadIdx.x == 0) s_any = 0;
    __syncthreads();
    int any = 0;
    for (int k = threadIdx.x; k < 16384; k += 256)
        if (words[k] > 1u) any = 1;
    if (any) atomicOr(&s_any, 1);
    __syncthreads();
    if (threadIdx.x == 0) *flag = s_any;
}

__global__ __launch_bounds__(256) void ncn_direct(
    const int* __restrict__ links, const void* __restrict__ adjv,
    const float* __restrict__ emb, float* __restrict__ out,
    const int* __restrict__ flag, int n_links)
{
    const int link = blockIdx.x;
    if (link >= n_links) return;
    const int i = links[2 * link];
    const int j = links[2 * link + 1];

    __shared__ int s_list[LIST_CAP];
    __shared__ int s_count;
    if (threadIdx.x == 0) s_count = 0;
    __syncthreads();

    const int byte_layout = flag ? flag[0] : 0;
    if (byte_layout) {
        const uint4* rowi = reinterpret_cast<const uint4*>(
            (const unsigned char*)adjv + (size_t)i * N_NODES);
        const uint4* rowj = reinterpret_cast<const uint4*>(
            (const unsigned char*)adjv + (size_t)j * N_NODES);
#pragma unroll
        for (int c = 0; c < 4; ++c) {
            const int idx = c * 256 + threadIdx.x;
            const uint4 a = rowi[idx];
            const uint4 b = rowj[idx];
            unsigned int m[4] = {a.x & b.x, a.y & b.y, a.z & b.z, a.w & b.w};
            if (m[0] | m[1] | m[2] | m[3]) {
                const int base = idx * 16;
#pragma unroll
                for (int w = 0; w < 4; ++w) {
                    unsigned int v = m[w];
                    if (!v) continue;
#pragma unroll
                    for (int b8 = 0; b8 < 4; ++b8) {
                        if ((v >> (8 * b8)) & 0xFFu) {
                            int pos = atomicAdd(&s_count, 1);
                            if (pos < LIST_CAP) s_list[pos] = base + w * 4 + b8;
                        }
                    }
                }
            }
        }
    } else {
        const uint4* rowi = reinterpret_cast<const uint4*>(
            (const int*)adjv + (size_t)i * N_NODES);
        const uint4* rowj = reinterpret_cast<const uint4*>(
            (const int*)adjv + (size_t)j * N_NODES);
#pragma unroll
        for (int c = 0; c < 16; ++c) {
            const int idx = c * 256 + threadIdx.x;
            const uint4 a = rowi[idx];
            const uint4 b = rowj[idx];
            const int base = idx * 4;
            if (a.x & b.x) { int p = atomicAdd(&s_count, 1); if (p < LIST_CAP) s_list[p] = base + 0; }
            if (a.y & b.y) { int p = atomicAdd(&s_count, 1); if (p < LIST_CAP) s_list[p] = base + 1; }
            if (a.z & b.z) { int p = atomicAdd(&s_count, 1); if (p < LIST_CAP) s_list[p] = base + 2; }
            if (a.w & b.w) { int p = atomicAdd(&s_count, 1); if (p < LIST_CAP) s_list[p] = base + 3; }
        }
    }
    __syncthreads();

    int count = s_count;
    if (count > LIST_CAP) count = LIST_CAP;

    const int t = threadIdx.x;
    const size_t obase = (size_t)link * (2 * D_EMB);
    if (t < D_EMB) {
        out[obase + t] = emb[(size_t)i * D_EMB + t] * emb[(size_t)j * D_EMB + t];
    } else {
        const int d = t - D_EMB;
        float s = 0.0f;
        for (int c = 0; c < count; ++c)
            s += emb[(size_t)s_list[c] * D_EMB + d];
        out[obase + D_EMB + d] = s;
    }
}

extern "C" void kernel_launch(void* const* d_in, const int* in_sizes, int n_in,
                              void* d_out, int out_size, void* d_ws, size_t ws_size,
                              hipStream_t stream) {
    const int* links = (const int*)d_in[0];     // int32 [n_links][2]
    const void* adj = d_in[1];                  // bool matrix (encoding probed)
    const float* emb = (const float*)d_in[2];   // fp32 [N_NODES][D_EMB]
    float* out = (float*)d_out;

    const int n_links = in_sizes[0] / 2;

    if (ws_size >= WS_NEEDED) {
        int* flags = (int*)d_ws;
        unsigned int* bm = (unsigned int*)((char*)d_ws + BM_OFF_BYTES);
        zero_probe_kernel<<<N_NODES / 256, 256, 0, stream>>>(
            (const unsigned int*)adj, flags);
        mark_kernel<<<(2 * n_links + 255) / 256, 256, 0, stream>>>(
            links, flags, 2 * n_links);
        // Both compress variants self-gate on the device-side layout flag;
        // only the matching one does work.
        compress_ballot_kernel<<<N_NODES, 256, 0, stream>>>(
            (const int*)adj, flags, bm);
        compress_byte_kernel<<<N_NODES, 256, 0, stream>>>(
            (const unsigned char*)adj, flags, bm);
        link_kernel<<<n_links, 256, 0, stream>>>(links, bm, emb, out, flags, n_links);
    } else {
        int* flag = (ws_size >= sizeof(int)) ? (int*)d_ws : nullptr;
        if (flag) detect_layout_kernel<<<1, 256, 0, stream>>>(
            (const unsigned int*)adj, flag);
        ncn_direct<<<n_links, 256, 0, stream>>>(links, adj, emb, out, flag, n_links);
    }
}

// Round 6
// 176.108 us; speedup vs baseline: 1.0202x; 1.0202x over previous
//
#include <hip/hip_runtime.h>

// Problem constants (from reference)
#define N_NODES 16384
#define D_EMB   128
#define LIST_CAP 1024          // max common neighbors (max degree ~200 incl. i==j)
#define BM_WORDS 512           // 16384 bits / 32 per compressed row (2 KB)
#define BM_U64   256           // u64 words per row
#define FLAG_OFF N_NODES       // int index of layout flag, right after used_flags
#define BM_OFF_BYTES (1 << 17) // bitmaps start at 128 KiB into ws
#define WS_NEEDED (BM_OFF_BYTES + (size_t)N_NODES * (BM_WORDS * 4)) // ~33.7 MB

// ---------------------------------------------------------------------------
// Pass 1: zero used-flags; block 0 also probes adjacency encoding.
// int32-bool: first 16384 words all in {0,1}; byte-bool: some word >1 w.p. ~1.
__global__ __launch_bounds__(256) void zero_probe_kernel(
    const unsigned int* __restrict__ words, int* __restrict__ flags)
{
    const int idx = blockIdx.x * 256 + threadIdx.x;  // grid 64 -> 16384 ints
    flags[idx] = 0;
    if (blockIdx.x == 0) {
        __shared__ int s_any;
        if (threadIdx.x == 0) s_any = 0;
        __syncthreads();
        int any = 0;
        for (int k = threadIdx.x; k < 16384; k += 256)
            if (words[k] > 1u) any = 1;
        if (any) atomicOr(&s_any, 1);
        __syncthreads();
        if (threadIdx.x == 0) flags[FLAG_OFF] = s_any;  // 1 => byte layout
    }
}

// Pass 2: mark rows referenced by any link endpoint (idempotent stores).
__global__ __launch_bounds__(256) void mark_kernel(
    const int* __restrict__ links, int* __restrict__ flags, int n_endpoints)
{
    const int k = blockIdx.x * 256 + threadIdx.x;
    if (k < n_endpoints) flags[links[k]] = 1;
}

// Pass 3 (int32 layout): streaming pack — R2-style hot loop.
// No ballots, no LDS, no barriers, no per-iter stores. Thread t, iter k loads
// uint4 at [k*256 + t] (lane-contiguous 4 KB per block-iteration); min(v,1u)
// turns each int into a bit with plain VALU (no vcc); 16 nibbles accumulate
// into a private u64; ONE coalesced 8 B store per thread.
// PERMUTED layout: u64[t] bit b <-> node 8192*(b>>5) + 1024*((b&31)>>2)
//                                      + 4*t + (b&3).
__global__ __launch_bounds__(256) void compress_pack_kernel(
    const unsigned int* __restrict__ adj, const int* __restrict__ flags,
    unsigned long long* __restrict__ bm64)
{
    const int r = blockIdx.x;
    if (flags[FLAG_OFF] != 0) return;   // wrong layout for this variant
    if (!flags[r]) return;

    const int t = threadIdx.x;
    const uint4* row = reinterpret_cast<const uint4*>(adj + (size_t)r * N_NODES);

    unsigned int lo = 0u, hi = 0u;
#pragma unroll
    for (int k = 0; k < 8; ++k) {
        const uint4 v = row[k * 256 + t];
        const unsigned int nib = min(v.x, 1u) | (min(v.y, 1u) << 1)
                               | (min(v.z, 1u) << 2) | (min(v.w, 1u) << 3);
        lo |= nib << (4 * k);
    }
#pragma unroll
    for (int k = 8; k < 16; ++k) {
        const uint4 v = row[k * 256 + t];
        const unsigned int nib = min(v.x, 1u) | (min(v.y, 1u) << 1)
                               | (min(v.z, 1u) << 2) | (min(v.w, 1u) << 3);
        hi |= nib << (4 * (k - 8));
    }
    bm64[(size_t)r * BM_U64 + t] = ((unsigned long long)hi << 32) | lo;
}

// Pass 3 (byte layout, defensive): LDS packing, LINEAR bitmap layout
// (word w bit b <-> node 32*w + b, i.e. u64[t] bit b <-> node 64*t + b).
__global__ __launch_bounds__(256) void compress_byte_kernel(
    const unsigned char* __restrict__ adj, const int* __restrict__ flags,
    unsigned int* __restrict__ bm)
{
    const int r = blockIdx.x;
    if (flags[FLAG_OFF] == 0) return;   // wrong layout for this variant
    if (!flags[r]) return;
    unsigned int* dst = bm + (size_t)r * BM_WORDS;
    const int t = threadIdx.x;
    __shared__ unsigned int s_nib[256];

    const uint4* row = reinterpret_cast<const uint4*>(adj + (size_t)r * N_NODES);
#pragma unroll
    for (int c = 0; c < 4; ++c) {
        const uint4 v = row[c * 256 + t];               // nodes [(c*256+t)*16, +16)
        const unsigned int arr[4] = {v.x, v.y, v.z, v.w};
        unsigned int half = 0;
#pragma unroll
        for (int a = 0; a < 4; ++a)
#pragma unroll
            for (int bb = 0; bb < 4; ++bb)
                half |= ((((arr[a] >> (8 * bb)) & 0xFFu) ? 1u : 0u) << (a * 4 + bb));
        s_nib[t] = half;                                // 16 bits valid
        __syncthreads();
        if (t < 128)
            dst[c * 128 + t] = s_nib[t * 2] | (s_nib[t * 2 + 1] << 16);
        __syncthreads();
    }
}

// Pass 4: per link, one u64 AND per thread covers the whole row pair,
// decode set bits -> node indices (layout-dependent), then write
// [product(128) | cn_sum(128)].
__global__ __launch_bounds__(256) void link_kernel(
    const int* __restrict__ links, const unsigned long long* __restrict__ bm64,
    const float* __restrict__ emb, float* __restrict__ out,
    const int* __restrict__ flags, int n_links)
{
    const int link = blockIdx.x;
    if (link >= n_links) return;
    const int i = links[2 * link];
    const int j = links[2 * link + 1];
    const int byte_layout = flags[FLAG_OFF];

    __shared__ int s_list[LIST_CAP];
    __shared__ int s_count;
    if (threadIdx.x == 0) s_count = 0;
    __syncthreads();

    const int t = threadIdx.x;
    unsigned long long m = bm64[(size_t)i * BM_U64 + t]
                         & bm64[(size_t)j * BM_U64 + t];
    while (m) {
        const int b = __ffsll(m) - 1;
        m &= m - 1;
        // int32 layout (permuted pack): node = 8192*(b>>5) + 1024*((b&31)>>2)
        //                                      + 4*t + (b&3)
        // byte layout (linear):         node = 64*t + b
        const int node = byte_layout
            ? (t * 64 + b)
            : (((b >> 5) << 13) + (((b & 31) >> 2) << 10) + (t << 2) + (b & 3));
        const int pos = atomicAdd(&s_count, 1);
        if (pos < LIST_CAP) s_list[pos] = node;
    }
    __syncthreads();

    int count = s_count;
    if (count > LIST_CAP) count = LIST_CAP;

    const size_t obase = (size_t)link * (2 * D_EMB);
    if (t < D_EMB) {
        out[obase + t] = emb[(size_t)i * D_EMB + t] * emb[(size_t)j * D_EMB + t];
    } else {
        const int d = t - D_EMB;
        float s = 0.0f;
        for (int c = 0; c < count; ++c)
            s += emb[(size_t)s_list[c] * D_EMB + d];
        out[obase + D_EMB + d] = s;
    }
}

// ---------------------------------------------------------------------------
// Fallback (ws too small): direct kernel — reads both full rows per link.
__global__ __launch_bounds__(256) void detect_layout_kernel(
    const unsigned int* __restrict__ words, int* __restrict__ flag)
{
    __shared__ int s_any;
    if (threadIdx.x == 0) s_any = 0;
    __syncthreads();
    int any = 0;
    for (int k = threadIdx.x; k < 16384; k += 256)
        if (words[k] > 1u) any = 1;
    if (any) atomicOr(&s_any, 1);
    __syncthreads();
    if (threadIdx.x == 0) *flag = s_any;
}

__global__ __launch_bounds__(256) void ncn_direct(
    const int* __restrict__ links, const void* __restrict__ adjv,
    const float* __restrict__ emb, float* __restrict__ out,
    const int* __restrict__ flag, int n_links)
{
    const int link = blockIdx.x;
    if (link >= n_links) return;
    const int i = links[2 * link];
    const int j = links[2 * link + 1];

    __shared__ int s_list[LIST_CAP];
    __shared__ int s_count;
    if (threadIdx.x == 0) s_count = 0;
    __syncthreads();

    const int byte_layout = flag ? flag[0] : 0;
    if (byte_layout) {
        const uint4* rowi = reinterpret_cast<const uint4*>(
            (const unsigned char*)adjv + (size_t)i * N_NODES);
        const uint4* rowj = reinterpret_cast<const uint4*>(
            (const unsigned char*)adjv + (size_t)j * N_NODES);
#pragma unroll
        for (int c = 0; c < 4; ++c) {
            const int idx = c * 256 + threadIdx.x;
            const uint4 a = rowi[idx];
            const uint4 b = rowj[idx];
            unsigned int m[4] = {a.x & b.x, a.y & b.y, a.z & b.z, a.w & b.w};
            if (m[0] | m[1] | m[2] | m[3]) {
                const int base = idx * 16;
#pragma unroll
                for (int w = 0; w < 4; ++w) {
                    unsigned int v = m[w];
                    if (!v) continue;
#pragma unroll
                    for (int b8 = 0; b8 < 4; ++b8) {
                        if ((v >> (8 * b8)) & 0xFFu) {
                            int pos = atomicAdd(&s_count, 1);
                            if (pos < LIST_CAP) s_list[pos] = base + w * 4 + b8;
                        }
                    }
                }
            }
        }
    } else {
        const uint4* rowi = reinterpret_cast<const uint4*>(
            (const int*)adjv + (size_t)i * N_NODES);
        const uint4* rowj = reinterpret_cast<const uint4*>(
            (const int*)adjv + (size_t)j * N_NODES);
#pragma unroll
        for (int c = 0; c < 16; ++c) {
            const int idx = c * 256 + threadIdx.x;
            const uint4 a = rowi[idx];
            const uint4 b = rowj[idx];
            const int base = idx * 4;
            if (a.x & b.x) { int p = atomicAdd(&s_count, 1); if (p < LIST_CAP) s_list[p] = base + 0; }
            if (a.y & b.y) { int p = atomicAdd(&s_count, 1); if (p < LIST_CAP) s_list[p] = base + 1; }
            if (a.z & b.z) { int p = atomicAdd(&s_count, 1); if (p < LIST_CAP) s_list[p] = base + 2; }
            if (a.w & b.w) { int p = atomicAdd(&s_count, 1); if (p < LIST_CAP) s_list[p] = base + 3; }
        }
    }
    __syncthreads();

    int count = s_count;
    if (count > LIST_CAP) count = LIST_CAP;

    const int t = threadIdx.x;
    const size_t obase = (size_t)link * (2 * D_EMB);
    if (t < D_EMB) {
        out[obase + t] = emb[(size_t)i * D_EMB + t] * emb[(size_t)j * D_EMB + t];
    } else {
        const int d = t - D_EMB;
        float s = 0.0f;
        for (int c = 0; c < count; ++c)
            s += emb[(size_t)s_list[c] * D_EMB + d];
        out[obase + D_EMB + d] = s;
    }
}

extern "C" void kernel_launch(void* const* d_in, const int* in_sizes, int n_in,
                              void* d_out, int out_size, void* d_ws, size_t ws_size,
                              hipStream_t stream) {
    const int* links = (const int*)d_in[0];     // int32 [n_links][2]
    const void* adj = d_in[1];                  // bool matrix (encoding probed)
    const float* emb = (const float*)d_in[2];   // fp32 [N_NODES][D_EMB]
    float* out = (float*)d_out;

    const int n_links = in_sizes[0] / 2;

    if (ws_size >= WS_NEEDED) {
        int* flags = (int*)d_ws;
        unsigned long long* bm64 =
            (unsigned long long*)((char*)d_ws + BM_OFF_BYTES);
        zero_probe_kernel<<<N_NODES / 256, 256, 0, stream>>>(
            (const unsigned int*)adj, flags);
        mark_kernel<<<(2 * n_links + 255) / 256, 256, 0, stream>>>(
            links, flags, 2 * n_links);
        // Both compress variants self-gate on the device-side layout flag.
        compress_pack_kernel<<<N_NODES, 256, 0, stream>>>(
            (const unsigned int*)adj, flags, bm64);
        compress_byte_kernel<<<N_NODES, 256, 0, stream>>>(
            (const unsigned char*)adj, flags, (unsigned int*)bm64);
        link_kernel<<<n_links, 256, 0, stream>>>(
            links, bm64, emb, out, flags, n_links);
    } else {
        int* flag = (ws_size >= sizeof(int)) ? (int*)d_ws : nullptr;
        if (flag) detect_layout_kernel<<<1, 256, 0, stream>>>(
            (const unsigned int*)adj, flag);
        ncn_direct<<<n_links, 256, 0, stream>>>(links, adj, emb, out, flag, n_links);
    }
}